// Round 4
// baseline (152.481 us; speedup 1.0000x reference)
//
#include <hip/hip_runtime.h>

// LoRA forward: out = (h @ B^T) @ A^T, h: (16384, 4096) f32, rank 16.
// R4: fused read/write interleave. Block = 64 rows as 4 sub-tiles of 16.
// While sub-tile t streams its h chunks (LDS dbuf, global_load_lds w=16),
// sub-tile t-1's output rows are computed from hr (LDS ping-pong) and
// nt-stored — mixing HBM read+write streams instead of phase-serializing.
// B is co-staged per chunk into LDS (L2-resident source, broadcast reads).

constexpr int D      = 4096;
constexpr int RK     = 16;
constexpr int SROWS  = 16;          // rows per sub-tile
constexpr int NSUB   = 4;           // sub-tiles per block (64 rows total)
constexpr int CHUNK  = 256;         // floats of d per chunk (1 KB/row)
constexpr int NCH    = D / CHUNK;   // 16

typedef float f32x4 __attribute__((ext_vector_type(4)));

__device__ __forceinline__ void gload_lds16(const float* src, float* ldsdst) {
  __builtin_amdgcn_global_load_lds(
      (const __attribute__((address_space(1))) void*)src,
      (__attribute__((address_space(3))) void*)ldsdst, 16, 0, 0);
}

__device__ __forceinline__ float dot4(float4 a, float4 b) {
  return a.x * b.x + a.y * b.y + a.z * b.z + a.w * b.w;
}

__global__ __launch_bounds__(1024) void lora_kernel(
    const float* __restrict__ h,
    const float* __restrict__ matA,   // (D, RK) row-major
    const float* __restrict__ matB,   // (RK, D) row-major
    float* __restrict__ out) {
  __shared__ float sH[2][SROWS][CHUNK];   // 32 KB  h chunk dbuf (swizzled)
  __shared__ float sB[2][RK][CHUNK];      // 32 KB  B chunk dbuf (linear)
  __shared__ float hrp[16][RK][SROWS];    // 16 KB  per-wave partials
  __shared__ float hrbuf[2][SROWS][RK];   //  2 KB  hr ping-pong

  const int tid = threadIdx.x;
  const int w   = __builtin_amdgcn_readfirstlane(tid >> 6);  // wave 0..15
  const int l   = tid & 63;
  const int g   = l >> 4;    // lane group 0..3
  const int r16 = l & 15;    // my h-row within sub-tile
  const long row0 = (long)blockIdx.x * 64;

  // ---- A fragment: 4 contiguous output cols per thread, reused 64x --------
  const int c0 = tid * 4;
  float4 a[4][4];
#pragma unroll
  for (int j = 0; j < 4; ++j)
#pragma unroll
    for (int q = 0; q < 4; ++q)
      a[j][q] = *reinterpret_cast<const float4*>(matA + (long)(c0 + j) * RK + q * 4);

  // ---- stage chunk c of sub-tile t into buffer b --------------------------
  // Wave w stages h-row w (XOR-swizzled source: LDS slot s holds global slot
  // s^w) and B-row w (linear). 2 global_load_lds per wave per chunk.
  auto STAGE = [&](int b, int t, int c) {
    const float* hsrc =
        h + (row0 + t * SROWS + w) * (long)D + c * CHUNK + ((l ^ w) * 4);
    gload_lds16(hsrc, &sH[b][w][0]);
    const float* bsrc = matB + (long)w * D + c * CHUNK + l * 4;
    gload_lds16(bsrc, &sB[b][w][0]);
  };

  float acc[RK];
#pragma unroll
  for (int r = 0; r < RK; ++r) acc[r] = 0.f;

  STAGE(0, 0, 0);

  for (int t = 0; t < NSUB; ++t) {
#pragma unroll 1
    for (int c = 0; c < NCH; ++c) {
      const bool last = (t == NSUB - 1) && (c == NCH - 1);
      // issue next chunk's loads first (deepest overlap)
      if (!last) {
        const int nt_ = (c + 1 < NCH) ? t : t + 1;
        const int nc  = (c + 1 < NCH) ? c + 1 : 0;
        STAGE((c + 1) & 1, nt_, nc);
      }
      // interleaved write: row c of sub-tile t-1 (16 KB across the block)
      if (t > 0) {
        const float4* hv =
            reinterpret_cast<const float4*>(&hrbuf[(t - 1) & 1][c][0]);
        const float4 h0 = hv[0], h1 = hv[1], h2 = hv[2], h3 = hv[3];
        f32x4 o;
        o.x = dot4(h0, a[0][0]) + dot4(h1, a[0][1]) + dot4(h2, a[0][2]) +
              dot4(h3, a[0][3]);
        o.y = dot4(h0, a[1][0]) + dot4(h1, a[1][1]) + dot4(h2, a[1][2]) +
              dot4(h3, a[1][3]);
        o.z = dot4(h0, a[2][0]) + dot4(h1, a[2][1]) + dot4(h2, a[2][2]) +
              dot4(h3, a[2][3]);
        o.w = dot4(h0, a[3][0]) + dot4(h1, a[3][1]) + dot4(h2, a[3][2]) +
              dot4(h3, a[3][3]);
        __builtin_nontemporal_store(
            o, reinterpret_cast<f32x4*>(
                   out + (row0 + (t - 1) * SROWS + c) * (long)D + c0));
      }
      // wait for chunk c's loads; leave next chunk's (+ store) in flight.
      // issue order per iter: [H_c,B_c](prev) ... [H_n,B_n][store]
      if (last) {
        asm volatile("s_waitcnt vmcnt(1)" ::: "memory");
      } else if (t > 0) {
        asm volatile("s_waitcnt vmcnt(3)" ::: "memory");
      } else {
        asm volatile("s_waitcnt vmcnt(2)" ::: "memory");
      }
      __builtin_amdgcn_s_barrier();
      __builtin_amdgcn_sched_barrier(0);

      // stage-1 compute: thread (w,l) -> (row r16, slice w*4+g) of chunk c
      const int buf = c & 1;
      const float4 h4 = *reinterpret_cast<const float4*>(
          &sH[buf][r16][(((w * 4 + g) ^ r16) * 4)]);  // deswizzle
#pragma unroll
      for (int r = 0; r < RK; ++r) {
        const float4 b4 = *reinterpret_cast<const float4*>(
            &sB[buf][r][(w * 4 + g) * 4]);  // 4-group broadcast, conflict-free
        acc[r] += dot4(h4, b4);
      }
      asm volatile("" ::: "memory");
      __builtin_amdgcn_s_barrier();  // computes done before buf overwrite
      __builtin_amdgcn_sched_barrier(0);
    }

    // ---- per-sub-tile reduce (raw barriers: do NOT drain vmcnt — next
    // sub-tile's chunk-0 loads are in flight) ------------------------------
#pragma unroll
    for (int r = 0; r < RK; ++r) {
      acc[r] += __shfl_xor(acc[r], 16, 64);
      acc[r] += __shfl_xor(acc[r], 32, 64);
    }
    if (l < 16) {
#pragma unroll
      for (int r = 0; r < RK; ++r) hrp[w][r][l] = acc[r];
    }
    asm volatile("s_waitcnt lgkmcnt(0)" ::: "memory");
    __builtin_amdgcn_s_barrier();
    __builtin_amdgcn_sched_barrier(0);
    if (tid < 256) {
      const int rr = tid & 15, r = tid >> 4;
      float s = 0.f;
#pragma unroll
      for (int w2 = 0; w2 < 16; ++w2) s += hrp[w2][r][rr];
      hrbuf[t & 1][rr][r] = s;
    }
    asm volatile("s_waitcnt lgkmcnt(0)" ::: "memory");
    __builtin_amdgcn_s_barrier();
    __builtin_amdgcn_sched_barrier(0);
#pragma unroll
    for (int r = 0; r < RK; ++r) acc[r] = 0.f;
  }

  // ---- epilogue: write sub-tile NSUB-1 ------------------------------------
  for (int rr = 0; rr < SROWS; ++rr) {
    const float4* hv =
        reinterpret_cast<const float4*>(&hrbuf[(NSUB - 1) & 1][rr][0]);
    const float4 h0 = hv[0], h1 = hv[1], h2 = hv[2], h3 = hv[3];
    f32x4 o;
    o.x = dot4(h0, a[0][0]) + dot4(h1, a[0][1]) + dot4(h2, a[0][2]) +
          dot4(h3, a[0][3]);
    o.y = dot4(h0, a[1][0]) + dot4(h1, a[1][1]) + dot4(h2, a[1][2]) +
          dot4(h3, a[1][3]);
    o.z = dot4(h0, a[2][0]) + dot4(h1, a[2][1]) + dot4(h2, a[2][2]) +
          dot4(h3, a[2][3]);
    o.w = dot4(h0, a[3][0]) + dot4(h1, a[3][1]) + dot4(h2, a[3][2]) +
          dot4(h3, a[3][3]);
    __builtin_nontemporal_store(
        o, reinterpret_cast<f32x4*>(
               out + (row0 + (NSUB - 1) * SROWS + rr) * (long)D + c0));
  }
}

extern "C" void kernel_launch(void* const* d_in, const int* in_sizes, int n_in,
                              void* d_out, int out_size, void* d_ws,
                              size_t ws_size, hipStream_t stream) {
  const float* h    = (const float*)d_in[0];
  const float* matA = (const float*)d_in[1];
  const float* matB = (const float*)d_in[2];
  float* out        = (float*)d_out;

  const long M = (long)in_sizes[0] / D;   // 16384 rows
  const int nblocks = (int)(M / 64);      // 256 blocks, 1 per CU
  hipLaunchKernelGGL(lora_kernel, dim3(nblocks), dim3(1024), 0, stream,
                     h, matA, matB, out);
}

// Round 5
// 121.117 us; speedup vs baseline: 1.2590x; 1.2590x over previous
//
#include <hip/hip_runtime.h>

// LoRA forward: out = (h @ B^T) @ A^T, h: (16384, 4096) f32, rank 16.
// R5: two-kernel split.
//  K1: hr[16384][16] = h @ B^T.  1024 blocks x 256 thr (4 waves, 16 rows),
//      LDS dbuf staging of h (XOR pre-swizzled source) + B, counted vmcnt,
//      small independent barrier domains (4 blocks/CU).
//  K2: out = hr @ A^T.  1024 blocks x 256 thr, A fragment in VGPRs, hr via
//      wave-uniform loads, nontemporal float4 stores. Barrier-free.

constexpr int D  = 4096;
constexpr int RK = 16;

typedef float f32x4 __attribute__((ext_vector_type(4)));

__device__ __forceinline__ void gload_lds16(const float* src, float* ldsdst) {
  __builtin_amdgcn_global_load_lds(
      (const __attribute__((address_space(1))) void*)src,
      (__attribute__((address_space(3))) void*)ldsdst, 16, 0, 0);
}

__device__ __forceinline__ float dot4(float4 a, float4 b) {
  return a.x * b.x + a.y * b.y + a.z * b.z + a.w * b.w;
}

// ---------------------------------------------------------------- K1 -------
constexpr int K1_ROWS = 16;
constexpr int K1_CH   = 128;          // floats of d per chunk (512 B/row)
constexpr int K1_NCH  = D / K1_CH;    // 32

__global__ __launch_bounds__(256) void lora_k1(
    const float* __restrict__ h,
    const float* __restrict__ matB,   // (RK, D) row-major
    float* __restrict__ hr) {         // (M, RK)
  __shared__ float sH[2][K1_ROWS][K1_CH];  // 16 KB dbuf (XOR-swizzled slots)
  __shared__ float sB[2][RK][K1_CH];       // 16 KB dbuf (linear)
  __shared__ float part[4][K1_ROWS][RK];   //  4 KB

  const int tid = threadIdx.x;
  const int w   = __builtin_amdgcn_readfirstlane(tid >> 6);  // wave 0..3
  const int l   = tid & 63;
  const long row0 = (long)blockIdx.x * K1_ROWS;

  // Per chunk: sH = 8 KB = 8 wave-loads, sB = 8 KB = 8 wave-loads.
  // Wave w issues loads i = 2w, 2w+1 of each. A 1-KB wave-load covers two
  // 512-B rows; lane l -> row 2i+(l>>5), 16-B slot l&31.
  auto STAGE = [&](int b, int c) {
#pragma unroll
    for (int j = 0; j < 2; ++j) {
      const int i = 2 * w + j;
      const int R = 2 * i + (l >> 5);      // h-row in tile
      const int sd = l & 31;               // dest slot (linear)
      // LDS[R][slot sd] <- h[R][slot sd ^ (R&15)]  (16-B slots)
      const float* hsrc =
          h + (row0 + R) * (long)D + c * K1_CH + ((sd ^ (R & 15)) * 4);
      gload_lds16(hsrc, &sH[b][2 * i][0]);
      const int Rb = 2 * i + (l >> 5);     // B rank-row
      const float* bsrc = matB + (long)Rb * D + c * K1_CH + (l & 31) * 4;
      gload_lds16(bsrc, &sB[b][2 * i][0]);
    }
  };

  float acc[RK];
#pragma unroll
  for (int r = 0; r < RK; ++r) acc[r] = 0.f;

  const int row = l & 15;               // my h-row
  const int ss  = (w << 2) + (l >> 4);  // my subslice 0..15 (8 floats each)

  STAGE(0, 0);
#pragma unroll 1
  for (int c = 0; c < K1_NCH; ++c) {
    if (c + 1 < K1_NCH) {
      STAGE((c + 1) & 1, c + 1);
      asm volatile("s_waitcnt vmcnt(4)" ::: "memory");  // chunk c landed
    } else {
      asm volatile("s_waitcnt vmcnt(0)" ::: "memory");
    }
    __builtin_amdgcn_s_barrier();
    __builtin_amdgcn_sched_barrier(0);

    const int buf = c & 1;
    const float* hrow = &sH[buf][row][0];
    float4 h4[2];
#pragma unroll
    for (int q = 0; q < 2; ++q)
      h4[q] = *reinterpret_cast<const float4*>(
          hrow + (((ss * 2 + q) ^ row) * 4));  // deswizzle
#pragma unroll
    for (int r = 0; r < RK; ++r) {
      const float4 b0 =
          *reinterpret_cast<const float4*>(&sB[buf][r][ss * 8]);
      const float4 b1 =
          *reinterpret_cast<const float4*>(&sB[buf][r][ss * 8 + 4]);
      acc[r] += dot4(h4[0], b0) + dot4(h4[1], b1);
    }
    asm volatile("" ::: "memory");
    __builtin_amdgcn_s_barrier();  // compute done before buf overwrite
    __builtin_amdgcn_sched_barrier(0);
  }

  // reduce 4 subslice-groups within wave, then 4 waves via LDS
#pragma unroll
  for (int r = 0; r < RK; ++r) {
    acc[r] += __shfl_xor(acc[r], 16, 64);
    acc[r] += __shfl_xor(acc[r], 32, 64);
  }
  if (l < 16) {
#pragma unroll
    for (int r = 0; r < RK; ++r) part[w][l][r] = acc[r];
  }
  __syncthreads();
  {
    const int orow = tid >> 4, rk = tid & 15;  // 256 = 16 rows x 16 ranks
    float s = 0.f;
#pragma unroll
    for (int w2 = 0; w2 < 4; ++w2) s += part[w2][orow][rk];
    hr[(row0 + orow) * RK + rk] = s;  // contiguous 1 KB per block; cacheable
  }
}

// ---------------------------------------------------------------- K2 -------
constexpr int K2_ROWS = 64;

__global__ __launch_bounds__(256) void lora_k2(
    const float* __restrict__ hr,     // (M, RK)
    const float* __restrict__ matA,   // (D, RK) row-major
    float* __restrict__ out) {
  const int tid = threadIdx.x;
  const int cs  = blockIdx.x & 3;        // column slice 0..3 (1024 cols)
  const long row0 = (long)(blockIdx.x >> 2) * K2_ROWS;
  const int c0 = cs * 1024 + tid * 4;    // 4 contiguous cols per thread

  float4 a[4][4];  // A rows for my 4 cols: 64 VGPRs, reused 64x
#pragma unroll
  for (int j = 0; j < 4; ++j)
#pragma unroll
    for (int q = 0; q < 4; ++q)
      a[j][q] = *reinterpret_cast<const float4*>(
          matA + (long)(c0 + j) * RK + q * 4);

#pragma unroll 4
  for (int rr = 0; rr < K2_ROWS; ++rr) {
    const float4* hv =
        reinterpret_cast<const float4*>(hr + (row0 + rr) * RK);  // uniform
    const float4 h0 = hv[0], h1 = hv[1], h2 = hv[2], h3 = hv[3];
    f32x4 o;
    o.x = dot4(h0, a[0][0]) + dot4(h1, a[0][1]) + dot4(h2, a[0][2]) +
          dot4(h3, a[0][3]);
    o.y = dot4(h0, a[1][0]) + dot4(h1, a[1][1]) + dot4(h2, a[1][2]) +
          dot4(h3, a[1][3]);
    o.z = dot4(h0, a[2][0]) + dot4(h1, a[2][1]) + dot4(h2, a[2][2]) +
          dot4(h3, a[2][3]);
    o.w = dot4(h0, a[3][0]) + dot4(h1, a[3][1]) + dot4(h2, a[3][2]) +
          dot4(h3, a[3][3]);
    __builtin_nontemporal_store(
        o, reinterpret_cast<f32x4*>(out + (row0 + rr) * (long)D + c0));
  }
}

extern "C" void kernel_launch(void* const* d_in, const int* in_sizes, int n_in,
                              void* d_out, int out_size, void* d_ws,
                              size_t ws_size, hipStream_t stream) {
  const float* h    = (const float*)d_in[0];
  const float* matA = (const float*)d_in[1];
  const float* matB = (const float*)d_in[2];
  float* out        = (float*)d_out;
  float* hr         = (float*)d_ws;   // M*RK*4 = 1 MiB scratch

  const long M = (long)in_sizes[0] / D;  // 16384 rows
  hipLaunchKernelGGL(lora_k1, dim3((int)(M / K1_ROWS)), dim3(256), 0, stream,
                     h, matB, hr);
  hipLaunchKernelGGL(lora_k2, dim3((int)(M / K2_ROWS) * 4), dim3(256), 0,
                     stream, hr, matA, out);
}